// Round 17
// baseline (270.058 us; speedup 1.0000x reference)
//
#include <hip/hip_runtime.h>

// Guided filter, B=2, H=W=1024, C=3, K=4, R=16, EPS=0.01.
// gf(x) = Vblur33(Hblur33(x)) - x  (separable Gaussian, center tap removed),
// N(y,x) = rowW(x)*colW(y) - 1 closed form.
//
// R2:  VT>8 register-rolling from GLOBAL spills (unroll budget).
// R4:  fewer bytes/elem didn't cut FETCH; cut redundancy structurally (LDS).
// R5:  64KB LDS tile -> 2 blocks/CU -> latency-bound. Keep LDS <= ~33KB.
// R8:  center round-trip deleted algebraically (s0 in k_solve); bf16 planes.
// R9-R11: >~64 live acc VGPRs crosses the 128-VGPR occupancy cliff.
// R14: vblur 128x64 tile, 2 threads/col: redundancy 1.5x, 24KB LDS.
// R15 lesson: cross-block L2 row-sharing fails across 8 XCDs; stride-3 LDS
//   gathers conflict. R16: batch folded into grids, 7 launches. BEST=270us.
// R17: hblur staging wrote 4 scalar ds_write_b32 at 16B lane stride = 8-way
//   bank conflict (11M cycles = 28% of kernel). Compose float4 in regs ->
//   single ds_write_b128 (natural conflict-free pattern).

#define HH 1024
#define WW 1024
#define HWSZ (HH * WW)
#define RR 16
#define NT 33
#define EPSF 0.01f

#define VBY 64                 // output rows per vblur block
#define VROWS (VBY + 2 * RR)   // 96 staged rows
#define VCOLS 128              // columns per vblur block (2 threads/column)

// per-batch u16-element offsets within the 50-bf16-plane (100MB) region
#define REG_U16   (50 * (size_t)HWSZ)
#define PR_OFF    0
#define HB1_OFF   (25 * (size_t)HWSZ)
#define M_OFF     0
#define AB_OFF    (25 * (size_t)HWSZ)
#define S0_OFF    (41 * (size_t)HWSZ)   // cast to float*: 4 fp32 planes
#define HB2_OFF   0
#define MB_OFF    (16 * (size_t)HWSZ)

typedef unsigned short u16;
typedef unsigned int u32;
typedef float v2f __attribute__((ext_vector_type(2)));

// exp(-d^2/32), d = i-16, computed offline (theta = 4).
__device__ constexpr float WG[NT] = {
  0.000335463f, 0.000883827f, 0.002187492f, 0.005086072f, 0.011108997f,
  0.022794173f, 0.043936928f, 0.079559512f, 0.135335283f, 0.216265076f,
  0.324652467f, 0.457833362f, 0.606530660f, 0.754839602f, 0.882496903f,
  0.969233234f, 1.0f,         0.969233234f, 0.882496903f, 0.754839602f,
  0.606530660f, 0.457833362f, 0.324652467f, 0.216265076f, 0.135335283f,
  0.079559512f, 0.043936928f, 0.022794173f, 0.011108997f, 0.005086072f,
  0.002187492f, 0.000883827f, 0.000335463f
};

__device__ constexpr float wg_sum() {
  float s = 0.0f;
  for (int i = 0; i < NT; ++i) s += WG[i];
  return s;
}

__device__ __forceinline__ u16 f2bf(float f) {  // round-to-nearest-even
  u32 u = __float_as_uint(f);
  u += 0x7fffu + ((u >> 16) & 1u);
  return (u16)(u >> 16);
}
__device__ __forceinline__ float bf2f(u16 v) { return __uint_as_float(((u32)v) << 16); }

// edge-aware 1D window weight at coordinate u in [0, n)
__device__ __forceinline__ float win_w(int u, int n) {
  constexpr float S = wg_sum();
  if (u >= RR && u < n - RR) return S;
  float w = 0.0f;
#pragma unroll
  for (int i = 0; i < NT; ++i) {
    const int uu = u - RR + i;
    if (uu >= 0 && uu < n) w += WG[i];
  }
  return w;
}

// ---------------------------------------------------------------------------
// K0: pointwise products -> 25 bf16 planes. 2 px/thread, u32 packed stores.
// Grid (HW/512, B), block 256.
// [0..2]=I, [3..6]=p, [7..18]=I_c*p_k (c*4+k), [19..24]=I_cI_c' sym.
// ---------------------------------------------------------------------------
__global__ __launch_bounds__(256) void k_products(const float* __restrict__ I,
                                                  const float* __restrict__ P,
                                                  u16* __restrict__ WS) {
  const int batch = blockIdx.y;
  const int t = blockIdx.x * 256 + threadIdx.x;  // pair index
  const float2* i2 = reinterpret_cast<const float2*>(I + (size_t)batch * HWSZ * 3);
  const float2 a = i2[3 * t], b = i2[3 * t + 1], c = i2[3 * t + 2];
  // px0: a.x a.y b.x   px1: b.y c.x c.y
  const float4* p4 = reinterpret_cast<const float4*>(P + (size_t)batch * HWSZ * 4);
  const float4 q0 = p4[2 * t], q1 = p4[2 * t + 1];

  const float iA[3] = {a.x, a.y, b.x};
  const float iB[3] = {b.y, c.x, c.y};
  const float pA[4] = {q0.x, q0.y, q0.z, q0.w};
  const float pB[4] = {q1.x, q1.y, q1.z, q1.w};

  u32* dst = reinterpret_cast<u32*>(WS + (size_t)batch * REG_U16 + PR_OFF) + t;
  const int half = HWSZ / 2;
#define ST(ch, va, vb) dst[(ch) * half] = (u32)f2bf(va) | ((u32)f2bf(vb) << 16)
  ST(0, iA[0], iB[0]); ST(1, iA[1], iB[1]); ST(2, iA[2], iB[2]);
  ST(3, pA[0], pB[0]); ST(4, pA[1], pB[1]); ST(5, pA[2], pB[2]); ST(6, pA[3], pB[3]);
#pragma unroll
  for (int cc = 0; cc < 3; ++cc)
#pragma unroll
    for (int k = 0; k < 4; ++k)
      ST(7 + cc * 4 + k, iA[cc] * pA[k], iB[cc] * pB[k]);
  ST(19, iA[0] * iA[0], iB[0] * iB[0]);
  ST(20, iA[0] * iA[1], iB[0] * iB[1]);
  ST(21, iA[0] * iA[2], iB[0] * iB[2]);
  ST(22, iA[1] * iA[1], iB[1] * iB[1]);
  ST(23, iA[1] * iA[2], iB[1] * iB[2]);
  ST(24, iA[2] * iA[2], iB[2] * iB[2]);
#undef ST
}

// ---------------------------------------------------------------------------
// K1: horizontal blur of NPL bf16 planes -> bf16. One full row per block,
//     4 outputs/thread via float4 LDS reads + register rolling.
//     Staging composes float4 in regs -> one ds_write_b128 (R17 fix).
//     Grid (H, NPL, B), block 256. srcOff/dstOff are u16 offsets in region.
// ---------------------------------------------------------------------------
__global__ __launch_bounds__(256) void k_hblur_bf(const u16* __restrict__ WS_c,
                                                  u16* __restrict__ WS,
                                                  size_t srcOff, size_t dstOff) {
  __shared__ float s[1056];  // 16 halo | 1024 row | 16 halo
  const int tid = threadIdx.x;
  const int y = blockIdx.x;
  const int ch = blockIdx.y;
  const int batch = blockIdx.z;
  const u16* src = WS_c + (size_t)batch * REG_U16 + srcOff +
                   (size_t)ch * HWSZ + y * WW;
  if (tid < 16) { s[tid] = 0.0f; s[1040 + tid] = 0.0f; }
  {
    const uint2 v = *reinterpret_cast<const uint2*>(src + 4 * tid);
    float4 f;
    f.x = bf2f((u16)v.x);
    f.y = bf2f((u16)(v.x >> 16));
    f.z = bf2f((u16)v.y);
    f.w = bf2f((u16)(v.y >> 16));
    *reinterpret_cast<float4*>(&s[16 + 4 * tid]) = f;  // single b128 write
  }
  __syncthreads();

  float vals[36];
  {
    const float4* s4 = reinterpret_cast<const float4*>(s) + tid;
#pragma unroll
    for (int r = 0; r < 9; ++r) {
      const float4 q = s4[r];
      vals[4 * r] = q.x; vals[4 * r + 1] = q.y;
      vals[4 * r + 2] = q.z; vals[4 * r + 3] = q.w;
    }
  }
  float acc[4] = {0.0f, 0.0f, 0.0f, 0.0f};
#pragma unroll
  for (int r = 0; r < 36; ++r) {
#pragma unroll
    for (int k = 0; k < 4; ++k) {
      const int dy = r - k;
      if (dy >= 0 && dy < NT) acc[k] += WG[dy] * vals[r];
    }
  }
  const u32 lo = (u32)f2bf(acc[0]) | ((u32)f2bf(acc[1]) << 16);
  const u32 hi = (u32)f2bf(acc[2]) | ((u32)f2bf(acc[3]) << 16);
  u16* dst = WS + (size_t)batch * REG_U16 + dstOff + (size_t)ch * HWSZ + y * WW;
  *reinterpret_cast<uint2*>(dst + 4 * tid) = make_uint2(lo, hi);
}

// ---------------------------------------------------------------------------
// K2: pure vertical blur of bf16 planes, LDS-staged 96x128 tile (24 KiB),
//     VBY=64 output rows per block; two threads per column (half = tid>>7).
//     Grid (W/128, H/64, NPL*B), block 256.
// ---------------------------------------------------------------------------
__global__ __launch_bounds__(256) void k_vblur(const u16* __restrict__ WS_c,
                                               u16* __restrict__ WS,
                                               size_t srcOff, size_t dstOff,
                                               int npl) {
  __shared__ u16 s[VROWS][VCOLS];  // 96 x 128 u16 = 24 KiB
  const int tid = threadIdx.x;
  const int bz = blockIdx.z;
  const int batch = bz / npl;
  const int ch = bz - batch * npl;
  const int xb = blockIdx.x * VCOLS;
  const int y0 = blockIdx.y * VBY;
  const int col = tid & (VCOLS - 1);
  const int half = tid >> 7;  // 0 or 1: rows y0..y0+31 / y0+32..y0+63

  {
    const u16* src = WS_c + (size_t)batch * REG_U16 + srcOff +
                     (size_t)ch * HWSZ + xb;
    uint4 tmp[6];
#pragma unroll
    for (int it = 0; it < 6; ++it) {
      const int id = it * 256 + tid;
      const int row = id >> 4;          // 0..95
      const int cir = id & 15;          // 16B chunk within row
      const int gy = y0 - RR + row;
      uint4 v = make_uint4(0u, 0u, 0u, 0u);
      if (gy >= 0 && gy < HH)
        v = *reinterpret_cast<const uint4*>(src + (size_t)gy * WW + cir * 8);
      tmp[it] = v;
    }
#pragma unroll
    for (int it = 0; it < 6; ++it) {
      const int id = it * 256 + tid;
      const int row = id >> 4;
      const int cir = id & 15;
      *reinterpret_cast<uint4*>(&s[row][cir * 8]) = tmp[it];
    }
  }
  __syncthreads();

  u16* dst = WS + (size_t)batch * REG_U16 + dstOff + (size_t)ch * HWSZ + xb + col;
  const int rbase = half * 32;  // local staged-row base for this half

  for (int c = 0; c < 4; ++c) {  // 4 chunks of 8 output rows
    v2f a[4];
#pragma unroll
    for (int q = 0; q < 4; ++q) a[q] = (v2f){0.0f, 0.0f};
#pragma unroll
    for (int r = 0; r < 40; ++r) {
      const float v = bf2f(s[rbase + 8 * c + r][col]);
#pragma unroll
      for (int q = 0; q < 4; ++q) {
        const int dy0 = r - 2 * q;      // row 2q
        const int dy1 = r - 2 * q - 1;  // row 2q+1
        const float wa = (dy0 >= 0 && dy0 < NT) ? WG[dy0] : 0.0f;
        const float wb = (dy1 >= 0 && dy1 < NT) ? WG[dy1] : 0.0f;
        if (wa != 0.0f || wb != 0.0f) {
          const v2f w = {wa, wb};
          a[q] += w * v;
        }
      }
    }
#pragma unroll
    for (int q = 0; q < 4; ++q) {
      const int yy = y0 + rbase + 8 * c + 2 * q;
      dst[(size_t)yy * WW] = f2bf(a[q].x);
      dst[(size_t)(yy + 1) * WW] = f2bf(a[q].y);
    }
  }
}

// ---------------------------------------------------------------------------
// K3: normalize (center subtract + /N) + pointwise 3x3 SPD solve with 4 RHS
//     -> 16 bf16 planes (a: c*4+k, b: 12+k) + fp32 s0[pix*4+k] = sum a*I_c+b.
//     Grid (HW/256, B), block 256.
// ---------------------------------------------------------------------------
__global__ __launch_bounds__(256) void k_solve(u16* __restrict__ WS,
                                               const float* __restrict__ I_,
                                               const float* __restrict__ P_) {
  const int batch = blockIdx.y;
  const int i = blockIdx.x * 256 + threadIdx.x;
  const int y = i >> 10;
  const int x = i & 1023;
  u16* reg = WS + (size_t)batch * REG_U16;
  const u16* M = reg + M_OFF;
  u16* AB = reg + AB_OFF;
  float* S0 = reinterpret_cast<float*>(reg + S0_OFF);
  const float* I = I_ + (size_t)batch * HWSZ * 3;
  const float* P = P_ + (size_t)batch * HWSZ * 4;
  const float invN = __builtin_amdgcn_rcpf(win_w(x, WW) * win_w(y, HH) - 1.0f);

  const float I0 = I[i * 3], I1 = I[i * 3 + 1], I2 = I[i * 3 + 2];
  float p[4];
#pragma unroll
  for (int k = 0; k < 4; ++k) p[k] = P[i * 4 + k];

  const float mI0 = (bf2f(M[i]) - I0) * invN;
  const float mI1 = (bf2f(M[HWSZ + i]) - I1) * invN;
  const float mI2 = (bf2f(M[2 * HWSZ + i]) - I2) * invN;
  float mp[4];
#pragma unroll
  for (int k = 0; k < 4; ++k) mp[k] = (bf2f(M[(3 + k) * HWSZ + i]) - p[k]) * invN;
  float cov[12];
#pragma unroll
  for (int k = 0; k < 4; ++k) {
    cov[k]     = (bf2f(M[(7 + k) * HWSZ + i])  - I0 * p[k]) * invN - mI0 * mp[k];
    cov[4 + k] = (bf2f(M[(11 + k) * HWSZ + i]) - I1 * p[k]) * invN - mI1 * mp[k];
    cov[8 + k] = (bf2f(M[(15 + k) * HWSZ + i]) - I2 * p[k]) * invN - mI2 * mp[k];
  }
  const float A00 = (bf2f(M[19 * HWSZ + i]) - I0 * I0) * invN - mI0 * mI0 + EPSF;
  const float A01 = (bf2f(M[20 * HWSZ + i]) - I0 * I1) * invN - mI0 * mI1;
  const float A02 = (bf2f(M[21 * HWSZ + i]) - I0 * I2) * invN - mI0 * mI2;
  const float A11 = (bf2f(M[22 * HWSZ + i]) - I1 * I1) * invN - mI1 * mI1 + EPSF;
  const float A12 = (bf2f(M[23 * HWSZ + i]) - I1 * I2) * invN - mI1 * mI2;
  const float A22 = (bf2f(M[24 * HWSZ + i]) - I2 * I2) * invN - mI2 * mI2 + EPSF;
  const float c00 = A11 * A22 - A12 * A12;
  const float c01 = A02 * A12 - A01 * A22;
  const float c02 = A01 * A12 - A02 * A11;
  const float det = A00 * c00 + A01 * c01 + A02 * c02;
  const float idet = 1.0f / det;
  const float i00 = c00 * idet, i01 = c01 * idet, i02 = c02 * idet;
  const float i11 = (A00 * A22 - A02 * A02) * idet;
  const float i12 = (A01 * A02 - A00 * A12) * idet;
  const float i22 = (A00 * A11 - A01 * A01) * idet;
  float4 s0;
  float* s0p = &s0.x;
#pragma unroll
  for (int k = 0; k < 4; ++k) {
    const float a0 = i00 * cov[k] + i01 * cov[4 + k] + i02 * cov[8 + k];
    const float a1 = i01 * cov[k] + i11 * cov[4 + k] + i12 * cov[8 + k];
    const float a2 = i02 * cov[k] + i12 * cov[4 + k] + i22 * cov[8 + k];
    const float b = mp[k] - (a0 * mI0 + a1 * mI1 + a2 * mI2);
    AB[k * HWSZ + i] = f2bf(a0);
    AB[(4 + k) * HWSZ + i] = f2bf(a1);
    AB[(8 + k) * HWSZ + i] = f2bf(a2);
    AB[(12 + k) * HWSZ + i] = f2bf(b);
    s0p[k] = a0 * I0 + a1 * I1 + a2 * I2 + b;
  }
  *reinterpret_cast<float4*>(S0 + (size_t)i * 4) = s0;
}

// ---------------------------------------------------------------------------
// K5b: combine q_k = (sum_c m~_a[c,k]*I_c + m~_b[k] - s0_k) * invN.
//      m~ are RAW blurs (bf16).  Grid (HW/256, B), block 256.
// ---------------------------------------------------------------------------
__global__ __launch_bounds__(256) void k_combine(const u16* __restrict__ WS,
                                                 const float* __restrict__ I_,
                                                 float* __restrict__ out_) {
  const int batch = blockIdx.y;
  const int i = blockIdx.x * 256 + threadIdx.x;
  const int y = i >> 10;
  const int x = i & 1023;
  const u16* reg = WS + (size_t)batch * REG_U16;
  const u16* MB = reg + MB_OFF;
  const float* S0 = reinterpret_cast<const float*>(reg + S0_OFF);
  const float* I = I_ + (size_t)batch * HWSZ * 3;
  float* out = out_ + (size_t)batch * HWSZ * 4;
  const float invN = __builtin_amdgcn_rcpf(win_w(x, WW) * win_w(y, HH) - 1.0f);
  float m[16];
#pragma unroll
  for (int ch = 0; ch < 16; ++ch) m[ch] = bf2f(MB[(size_t)ch * HWSZ + i]);
  const float i0 = I[i * 3], i1 = I[i * 3 + 1], i2 = I[i * 3 + 2];
  const float4 s0 = *reinterpret_cast<const float4*>(S0 + (size_t)i * 4);
  float4 q;
  q.x = (m[0] * i0 + m[4] * i1 + m[8]  * i2 + m[12] - s0.x) * invN;
  q.y = (m[1] * i0 + m[5] * i1 + m[9]  * i2 + m[13] - s0.y) * invN;
  q.z = (m[2] * i0 + m[6] * i1 + m[10] * i2 + m[14] - s0.z) * invN;
  q.w = (m[3] * i0 + m[7] * i1 + m[11] * i2 + m[15] - s0.w) * invN;
  *reinterpret_cast<float4*>(out + (size_t)i * 4) = q;
}

extern "C" void kernel_launch(void* const* d_in, const int* in_sizes, int n_in,
                              void* d_out, int out_size, void* d_ws, size_t ws_size,
                              hipStream_t stream) {
  const float* I = (const float*)d_in[0];
  const float* P = (const float*)d_in[1];
  float* out = (float*)d_out;
  u16* WS = (u16*)d_ws;  // 2 regions x 50 bf16 planes = 200 MB

  k_products<<<dim3(HWSZ / 512, 2), dim3(256), 0, stream>>>(I, P, WS);
  k_hblur_bf<<<dim3(HH, 25, 2), dim3(256), 0, stream>>>(WS, WS, PR_OFF, HB1_OFF);
  k_vblur<<<dim3(WW / VCOLS, HH / VBY, 25 * 2), dim3(256), 0, stream>>>(
      WS, WS, HB1_OFF, M_OFF, 25);
  k_solve<<<dim3(HWSZ / 256, 2), dim3(256), 0, stream>>>(WS, I, P);
  k_hblur_bf<<<dim3(HH, 16, 2), dim3(256), 0, stream>>>(WS, WS, AB_OFF, HB2_OFF);
  k_vblur<<<dim3(WW / VCOLS, HH / VBY, 16 * 2), dim3(256), 0, stream>>>(
      WS, WS, HB2_OFF, MB_OFF, 16);
  k_combine<<<dim3(HWSZ / 256, 2), dim3(256), 0, stream>>>(WS, I, out);
}

// Round 18
// 254.184 us; speedup vs baseline: 1.0624x; 1.0624x over previous
//
#include <hip/hip_runtime.h>

// Guided filter, B=2, H=W=1024, C=3, K=4, R=16, EPS=0.01.
// gf(x) = Vblur33(Hblur33(x)) - x  (separable Gaussian, center tap removed),
// N(y,x) = rowW(x)*colW(y) - 1 closed form.
//
// R2:  VT>8 register-rolling from GLOBAL spills (unroll budget).
// R4:  fewer bytes/elem didn't cut FETCH; cut redundancy structurally (LDS).
// R5:  64KB LDS tile -> 2 blocks/CU -> latency-bound. Keep LDS <= ~33KB.
// R8:  center round-trip deleted algebraically (s0 in k_solve); bf16 planes.
// R9-R11: >~64 live acc VGPRs crosses the 128-VGPR occupancy cliff.
// R14: vblur 128x64 tile, 2 threads/col: redundancy 1.5x, 24KB LDS.
// R15: cross-block L2 row-sharing fails across 8 XCDs. R16: batch in grids.
// R17 lesson: hblur's 11M "conflicts" are from the stride-16 b128 READS and
//   overlap with VALU anyway -- kernel is VALU-issue-bound (85%).
// R18: halve hblur's FMA stream via v_pk_fma_f32 over tap PAIRS: adjacent
//   vals floats are natural register pairs from the float4 LDS read, weight
//   pairs are uniform constants (SGPR pairs). 144 FMA -> 72 pk-FMA + 4 adds.

#define HH 1024
#define WW 1024
#define HWSZ (HH * WW)
#define RR 16
#define NT 33
#define EPSF 0.01f

#define VBY 64                 // output rows per vblur block
#define VROWS (VBY + 2 * RR)   // 96 staged rows
#define VCOLS 128              // columns per vblur block (2 threads/column)

// per-batch u16-element offsets within the 50-bf16-plane (100MB) region
#define REG_U16   (50 * (size_t)HWSZ)
#define PR_OFF    0
#define HB1_OFF   (25 * (size_t)HWSZ)
#define M_OFF     0
#define AB_OFF    (25 * (size_t)HWSZ)
#define S0_OFF    (41 * (size_t)HWSZ)   // cast to float*: 4 fp32 planes
#define HB2_OFF   0
#define MB_OFF    (16 * (size_t)HWSZ)

typedef unsigned short u16;
typedef unsigned int u32;
typedef float v2f __attribute__((ext_vector_type(2)));

// exp(-d^2/32), d = i-16, computed offline (theta = 4).
__device__ constexpr float WG[NT] = {
  0.000335463f, 0.000883827f, 0.002187492f, 0.005086072f, 0.011108997f,
  0.022794173f, 0.043936928f, 0.079559512f, 0.135335283f, 0.216265076f,
  0.324652467f, 0.457833362f, 0.606530660f, 0.754839602f, 0.882496903f,
  0.969233234f, 1.0f,         0.969233234f, 0.882496903f, 0.754839602f,
  0.606530660f, 0.457833362f, 0.324652467f, 0.216265076f, 0.135335283f,
  0.079559512f, 0.043936928f, 0.022794173f, 0.011108997f, 0.005086072f,
  0.002187492f, 0.000883827f, 0.000335463f
};

__device__ constexpr float wg_sum() {
  float s = 0.0f;
  for (int i = 0; i < NT; ++i) s += WG[i];
  return s;
}

// weight with range clamp, compile-time foldable
__device__ __forceinline__ constexpr float Wc(int j) {
  return (j >= 0 && j < NT) ? WG[j] : 0.0f;
}

__device__ __forceinline__ u16 f2bf(float f) {  // round-to-nearest-even
  u32 u = __float_as_uint(f);
  u += 0x7fffu + ((u >> 16) & 1u);
  return (u16)(u >> 16);
}
__device__ __forceinline__ float bf2f(u16 v) { return __uint_as_float(((u32)v) << 16); }

// edge-aware 1D window weight at coordinate u in [0, n)
__device__ __forceinline__ float win_w(int u, int n) {
  constexpr float S = wg_sum();
  if (u >= RR && u < n - RR) return S;
  float w = 0.0f;
#pragma unroll
  for (int i = 0; i < NT; ++i) {
    const int uu = u - RR + i;
    if (uu >= 0 && uu < n) w += WG[i];
  }
  return w;
}

// ---------------------------------------------------------------------------
// K0: pointwise products -> 25 bf16 planes. 2 px/thread, u32 packed stores.
// Grid (HW/512, B), block 256.
// [0..2]=I, [3..6]=p, [7..18]=I_c*p_k (c*4+k), [19..24]=I_cI_c' sym.
// ---------------------------------------------------------------------------
__global__ __launch_bounds__(256) void k_products(const float* __restrict__ I,
                                                  const float* __restrict__ P,
                                                  u16* __restrict__ WS) {
  const int batch = blockIdx.y;
  const int t = blockIdx.x * 256 + threadIdx.x;  // pair index
  const float2* i2 = reinterpret_cast<const float2*>(I + (size_t)batch * HWSZ * 3);
  const float2 a = i2[3 * t], b = i2[3 * t + 1], c = i2[3 * t + 2];
  // px0: a.x a.y b.x   px1: b.y c.x c.y
  const float4* p4 = reinterpret_cast<const float4*>(P + (size_t)batch * HWSZ * 4);
  const float4 q0 = p4[2 * t], q1 = p4[2 * t + 1];

  const float iA[3] = {a.x, a.y, b.x};
  const float iB[3] = {b.y, c.x, c.y};
  const float pA[4] = {q0.x, q0.y, q0.z, q0.w};
  const float pB[4] = {q1.x, q1.y, q1.z, q1.w};

  u32* dst = reinterpret_cast<u32*>(WS + (size_t)batch * REG_U16 + PR_OFF) + t;
  const int half = HWSZ / 2;
#define ST(ch, va, vb) dst[(ch) * half] = (u32)f2bf(va) | ((u32)f2bf(vb) << 16)
  ST(0, iA[0], iB[0]); ST(1, iA[1], iB[1]); ST(2, iA[2], iB[2]);
  ST(3, pA[0], pB[0]); ST(4, pA[1], pB[1]); ST(5, pA[2], pB[2]); ST(6, pA[3], pB[3]);
#pragma unroll
  for (int cc = 0; cc < 3; ++cc)
#pragma unroll
    for (int k = 0; k < 4; ++k)
      ST(7 + cc * 4 + k, iA[cc] * pA[k], iB[cc] * pB[k]);
  ST(19, iA[0] * iA[0], iB[0] * iB[0]);
  ST(20, iA[0] * iA[1], iB[0] * iB[1]);
  ST(21, iA[0] * iA[2], iB[0] * iB[2]);
  ST(22, iA[1] * iA[1], iB[1] * iB[1]);
  ST(23, iA[1] * iA[2], iB[1] * iB[2]);
  ST(24, iA[2] * iA[2], iB[2] * iB[2]);
#undef ST
}

// ---------------------------------------------------------------------------
// K1: horizontal blur of NPL bf16 planes -> bf16. One full row per block,
//     4 outputs/thread; FMA over tap pairs via packed fp32 (R18).
//     Grid (H, NPL, B), block 256. srcOff/dstOff are u16 offsets in region.
// ---------------------------------------------------------------------------
__global__ __launch_bounds__(256) void k_hblur_bf(const u16* __restrict__ WS_c,
                                                  u16* __restrict__ WS,
                                                  size_t srcOff, size_t dstOff) {
  __shared__ float s[1056];  // 16 halo | 1024 row | 16 halo
  const int tid = threadIdx.x;
  const int y = blockIdx.x;
  const int ch = blockIdx.y;
  const int batch = blockIdx.z;
  const u16* src = WS_c + (size_t)batch * REG_U16 + srcOff +
                   (size_t)ch * HWSZ + y * WW;
  if (tid < 16) { s[tid] = 0.0f; s[1040 + tid] = 0.0f; }
  {
    const uint2 v = *reinterpret_cast<const uint2*>(src + 4 * tid);
    float4 f;
    f.x = bf2f((u16)v.x);
    f.y = bf2f((u16)(v.x >> 16));
    f.z = bf2f((u16)v.y);
    f.w = bf2f((u16)(v.y >> 16));
    *reinterpret_cast<float4*>(&s[16 + 4 * tid]) = f;
  }
  __syncthreads();

  // outputs x=4t+k (k=0..3); window of out k covers s[4t+k .. 4t+k+32],
  // i.e. vals index j = 4*r4 + e with weight Wc(j - k).
  v2f acc[4];
#pragma unroll
  for (int k = 0; k < 4; ++k) acc[k] = (v2f){0.0f, 0.0f};
  {
    const float4* s4 = reinterpret_cast<const float4*>(s) + tid;
#pragma unroll
    for (int r4 = 0; r4 < 9; ++r4) {
      const float4 q = s4[r4];
      const v2f v01 = {q.x, q.y};
      const v2f v23 = {q.z, q.w};
#pragma unroll
      for (int k = 0; k < 4; ++k) {
        const int j0 = 4 * r4 - k;
        if (Wc(j0) != 0.0f || Wc(j0 + 1) != 0.0f)
          acc[k] += (v2f){Wc(j0), Wc(j0 + 1)} * v01;
        if (Wc(j0 + 2) != 0.0f || Wc(j0 + 3) != 0.0f)
          acc[k] += (v2f){Wc(j0 + 2), Wc(j0 + 3)} * v23;
      }
    }
  }
  float out[4];
#pragma unroll
  for (int k = 0; k < 4; ++k) out[k] = acc[k].x + acc[k].y;

  const u32 lo = (u32)f2bf(out[0]) | ((u32)f2bf(out[1]) << 16);
  const u32 hi = (u32)f2bf(out[2]) | ((u32)f2bf(out[3]) << 16);
  u16* dst = WS + (size_t)batch * REG_U16 + dstOff + (size_t)ch * HWSZ + y * WW;
  *reinterpret_cast<uint2*>(dst + 4 * tid) = make_uint2(lo, hi);
}

// ---------------------------------------------------------------------------
// K2: pure vertical blur of bf16 planes, LDS-staged 96x128 tile (24 KiB),
//     VBY=64 output rows per block; two threads per column (half = tid>>7).
//     Grid (W/128, H/64, NPL*B), block 256.
// ---------------------------------------------------------------------------
__global__ __launch_bounds__(256) void k_vblur(const u16* __restrict__ WS_c,
                                               u16* __restrict__ WS,
                                               size_t srcOff, size_t dstOff,
                                               int npl) {
  __shared__ u16 s[VROWS][VCOLS];  // 96 x 128 u16 = 24 KiB
  const int tid = threadIdx.x;
  const int bz = blockIdx.z;
  const int batch = bz / npl;
  const int ch = bz - batch * npl;
  const int xb = blockIdx.x * VCOLS;
  const int y0 = blockIdx.y * VBY;
  const int col = tid & (VCOLS - 1);
  const int half = tid >> 7;  // 0 or 1: rows y0..y0+31 / y0+32..y0+63

  {
    const u16* src = WS_c + (size_t)batch * REG_U16 + srcOff +
                     (size_t)ch * HWSZ + xb;
    uint4 tmp[6];
#pragma unroll
    for (int it = 0; it < 6; ++it) {
      const int id = it * 256 + tid;
      const int row = id >> 4;          // 0..95
      const int cir = id & 15;          // 16B chunk within row
      const int gy = y0 - RR + row;
      uint4 v = make_uint4(0u, 0u, 0u, 0u);
      if (gy >= 0 && gy < HH)
        v = *reinterpret_cast<const uint4*>(src + (size_t)gy * WW + cir * 8);
      tmp[it] = v;
    }
#pragma unroll
    for (int it = 0; it < 6; ++it) {
      const int id = it * 256 + tid;
      const int row = id >> 4;
      const int cir = id & 15;
      *reinterpret_cast<uint4*>(&s[row][cir * 8]) = tmp[it];
    }
  }
  __syncthreads();

  u16* dst = WS + (size_t)batch * REG_U16 + dstOff + (size_t)ch * HWSZ + xb + col;
  const int rbase = half * 32;  // local staged-row base for this half

  for (int c = 0; c < 4; ++c) {  // 4 chunks of 8 output rows
    v2f a[4];
#pragma unroll
    for (int q = 0; q < 4; ++q) a[q] = (v2f){0.0f, 0.0f};
#pragma unroll
    for (int r = 0; r < 40; ++r) {
      const float v = bf2f(s[rbase + 8 * c + r][col]);
#pragma unroll
      for (int q = 0; q < 4; ++q) {
        const int dy0 = r - 2 * q;      // row 2q
        const int dy1 = r - 2 * q - 1;  // row 2q+1
        const float wa = (dy0 >= 0 && dy0 < NT) ? WG[dy0] : 0.0f;
        const float wb = (dy1 >= 0 && dy1 < NT) ? WG[dy1] : 0.0f;
        if (wa != 0.0f || wb != 0.0f) {
          const v2f w = {wa, wb};
          a[q] += w * v;
        }
      }
    }
#pragma unroll
    for (int q = 0; q < 4; ++q) {
      const int yy = y0 + rbase + 8 * c + 2 * q;
      dst[(size_t)yy * WW] = f2bf(a[q].x);
      dst[(size_t)(yy + 1) * WW] = f2bf(a[q].y);
    }
  }
}

// ---------------------------------------------------------------------------
// K3: normalize (center subtract + /N) + pointwise 3x3 SPD solve with 4 RHS
//     -> 16 bf16 planes (a: c*4+k, b: 12+k) + fp32 s0[pix*4+k] = sum a*I_c+b.
//     Grid (HW/256, B), block 256.
// ---------------------------------------------------------------------------
__global__ __launch_bounds__(256) void k_solve(u16* __restrict__ WS,
                                               const float* __restrict__ I_,
                                               const float* __restrict__ P_) {
  const int batch = blockIdx.y;
  const int i = blockIdx.x * 256 + threadIdx.x;
  const int y = i >> 10;
  const int x = i & 1023;
  u16* reg = WS + (size_t)batch * REG_U16;
  const u16* M = reg + M_OFF;
  u16* AB = reg + AB_OFF;
  float* S0 = reinterpret_cast<float*>(reg + S0_OFF);
  const float* I = I_ + (size_t)batch * HWSZ * 3;
  const float* P = P_ + (size_t)batch * HWSZ * 4;
  const float invN = __builtin_amdgcn_rcpf(win_w(x, WW) * win_w(y, HH) - 1.0f);

  const float I0 = I[i * 3], I1 = I[i * 3 + 1], I2 = I[i * 3 + 2];
  float p[4];
#pragma unroll
  for (int k = 0; k < 4; ++k) p[k] = P[i * 4 + k];

  const float mI0 = (bf2f(M[i]) - I0) * invN;
  const float mI1 = (bf2f(M[HWSZ + i]) - I1) * invN;
  const float mI2 = (bf2f(M[2 * HWSZ + i]) - I2) * invN;
  float mp[4];
#pragma unroll
  for (int k = 0; k < 4; ++k) mp[k] = (bf2f(M[(3 + k) * HWSZ + i]) - p[k]) * invN;
  float cov[12];
#pragma unroll
  for (int k = 0; k < 4; ++k) {
    cov[k]     = (bf2f(M[(7 + k) * HWSZ + i])  - I0 * p[k]) * invN - mI0 * mp[k];
    cov[4 + k] = (bf2f(M[(11 + k) * HWSZ + i]) - I1 * p[k]) * invN - mI1 * mp[k];
    cov[8 + k] = (bf2f(M[(15 + k) * HWSZ + i]) - I2 * p[k]) * invN - mI2 * mp[k];
  }
  const float A00 = (bf2f(M[19 * HWSZ + i]) - I0 * I0) * invN - mI0 * mI0 + EPSF;
  const float A01 = (bf2f(M[20 * HWSZ + i]) - I0 * I1) * invN - mI0 * mI1;
  const float A02 = (bf2f(M[21 * HWSZ + i]) - I0 * I2) * invN - mI0 * mI2;
  const float A11 = (bf2f(M[22 * HWSZ + i]) - I1 * I1) * invN - mI1 * mI1 + EPSF;
  const float A12 = (bf2f(M[23 * HWSZ + i]) - I1 * I2) * invN - mI1 * mI2;
  const float A22 = (bf2f(M[24 * HWSZ + i]) - I2 * I2) * invN - mI2 * mI2 + EPSF;
  const float c00 = A11 * A22 - A12 * A12;
  const float c01 = A02 * A12 - A01 * A22;
  const float c02 = A01 * A12 - A02 * A11;
  const float det = A00 * c00 + A01 * c01 + A02 * c02;
  const float idet = 1.0f / det;
  const float i00 = c00 * idet, i01 = c01 * idet, i02 = c02 * idet;
  const float i11 = (A00 * A22 - A02 * A02) * idet;
  const float i12 = (A01 * A02 - A00 * A12) * idet;
  const float i22 = (A00 * A11 - A01 * A01) * idet;
  float4 s0;
  float* s0p = &s0.x;
#pragma unroll
  for (int k = 0; k < 4; ++k) {
    const float a0 = i00 * cov[k] + i01 * cov[4 + k] + i02 * cov[8 + k];
    const float a1 = i01 * cov[k] + i11 * cov[4 + k] + i12 * cov[8 + k];
    const float a2 = i02 * cov[k] + i12 * cov[4 + k] + i22 * cov[8 + k];
    const float b = mp[k] - (a0 * mI0 + a1 * mI1 + a2 * mI2);
    AB[k * HWSZ + i] = f2bf(a0);
    AB[(4 + k) * HWSZ + i] = f2bf(a1);
    AB[(8 + k) * HWSZ + i] = f2bf(a2);
    AB[(12 + k) * HWSZ + i] = f2bf(b);
    s0p[k] = a0 * I0 + a1 * I1 + a2 * I2 + b;
  }
  *reinterpret_cast<float4*>(S0 + (size_t)i * 4) = s0;
}

// ---------------------------------------------------------------------------
// K5b: combine q_k = (sum_c m~_a[c,k]*I_c + m~_b[k] - s0_k) * invN.
//      m~ are RAW blurs (bf16).  Grid (HW/256, B), block 256.
// ---------------------------------------------------------------------------
__global__ __launch_bounds__(256) void k_combine(const u16* __restrict__ WS,
                                                 const float* __restrict__ I_,
                                                 float* __restrict__ out_) {
  const int batch = blockIdx.y;
  const int i = blockIdx.x * 256 + threadIdx.x;
  const int y = i >> 10;
  const int x = i & 1023;
  const u16* reg = WS + (size_t)batch * REG_U16;
  const u16* MB = reg + MB_OFF;
  const float* S0 = reinterpret_cast<const float*>(reg + S0_OFF);
  const float* I = I_ + (size_t)batch * HWSZ * 3;
  float* out = out_ + (size_t)batch * HWSZ * 4;
  const float invN = __builtin_amdgcn_rcpf(win_w(x, WW) * win_w(y, HH) - 1.0f);
  float m[16];
#pragma unroll
  for (int ch = 0; ch < 16; ++ch) m[ch] = bf2f(MB[(size_t)ch * HWSZ + i]);
  const float i0 = I[i * 3], i1 = I[i * 3 + 1], i2 = I[i * 3 + 2];
  const float4 s0 = *reinterpret_cast<const float4*>(S0 + (size_t)i * 4);
  float4 q;
  q.x = (m[0] * i0 + m[4] * i1 + m[8]  * i2 + m[12] - s0.x) * invN;
  q.y = (m[1] * i0 + m[5] * i1 + m[9]  * i2 + m[13] - s0.y) * invN;
  q.z = (m[2] * i0 + m[6] * i1 + m[10] * i2 + m[14] - s0.z) * invN;
  q.w = (m[3] * i0 + m[7] * i1 + m[11] * i2 + m[15] - s0.w) * invN;
  *reinterpret_cast<float4*>(out + (size_t)i * 4) = q;
}

extern "C" void kernel_launch(void* const* d_in, const int* in_sizes, int n_in,
                              void* d_out, int out_size, void* d_ws, size_t ws_size,
                              hipStream_t stream) {
  const float* I = (const float*)d_in[0];
  const float* P = (const float*)d_in[1];
  float* out = (float*)d_out;
  u16* WS = (u16*)d_ws;  // 2 regions x 50 bf16 planes = 200 MB

  k_products<<<dim3(HWSZ / 512, 2), dim3(256), 0, stream>>>(I, P, WS);
  k_hblur_bf<<<dim3(HH, 25, 2), dim3(256), 0, stream>>>(WS, WS, PR_OFF, HB1_OFF);
  k_vblur<<<dim3(WW / VCOLS, HH / VBY, 25 * 2), dim3(256), 0, stream>>>(
      WS, WS, HB1_OFF, M_OFF, 25);
  k_solve<<<dim3(HWSZ / 256, 2), dim3(256), 0, stream>>>(WS, I, P);
  k_hblur_bf<<<dim3(HH, 16, 2), dim3(256), 0, stream>>>(WS, WS, AB_OFF, HB2_OFF);
  k_vblur<<<dim3(WW / VCOLS, HH / VBY, 16 * 2), dim3(256), 0, stream>>>(
      WS, WS, HB2_OFF, MB_OFF, 16);
  k_combine<<<dim3(HWSZ / 256, 2), dim3(256), 0, stream>>>(WS, I, out);
}

// Round 19
// 253.755 us; speedup vs baseline: 1.0642x; 1.0017x over previous
//
#include <hip/hip_runtime.h>

// Guided filter, B=2, H=W=1024, C=3, K=4, R=16, EPS=0.01.
// gf(x) = Vblur33(Hblur33(x)) - x  (separable Gaussian, center tap removed),
// N(y,x) = rowW(x)*colW(y) - 1 closed form.
//
// R2:  VT>8 register-rolling from GLOBAL spills (unroll budget).
// R4:  fewer bytes/elem didn't cut FETCH; cut redundancy structurally (LDS).
// R5:  64KB LDS tile -> 2 blocks/CU -> latency-bound. Keep LDS <= ~33KB.
// R8:  center round-trip deleted algebraically (s0 in k_solve); bf16 planes.
// R9-R11: >~64 live acc VGPRs crosses the 128-VGPR occupancy cliff.
// R14: vblur 128x64 tile: redundancy 1.5x, 24KB LDS. R16: batch in grids.
// R17 lesson: hblur was VALU-issue-bound, not LDS-bound.
// R18: hblur pk-FMA over tap pairs (270->254).
// R19: vblur remap: thread = 2 adjacent cols x 16 rows (cp=tid&63, grp=tid>>6).
//   u32 LDS reads (2 bf16 cols, 2-way alias = free), pk-FMA across columns
//   (broadcast weight), packed u32 stores. 160 u16 reads -> 80 u32; 4 chunk
//   loops -> 2; 32 u16 stores -> 16 u32. Chunk body = proven 40x8 roll.

#define HH 1024
#define WW 1024
#define HWSZ (HH * WW)
#define RR 16
#define NT 33
#define EPSF 0.01f

#define VBY 64                 // output rows per vblur block
#define VROWS (VBY + 2 * RR)   // 96 staged rows
#define VCOLS 128              // columns per vblur block

// per-batch u16-element offsets within the 50-bf16-plane (100MB) region
#define REG_U16   (50 * (size_t)HWSZ)
#define PR_OFF    0
#define HB1_OFF   (25 * (size_t)HWSZ)
#define M_OFF     0
#define AB_OFF    (25 * (size_t)HWSZ)
#define S0_OFF    (41 * (size_t)HWSZ)   // cast to float*: 4 fp32 planes
#define HB2_OFF   0
#define MB_OFF    (16 * (size_t)HWSZ)

typedef unsigned short u16;
typedef unsigned int u32;
typedef float v2f __attribute__((ext_vector_type(2)));

// exp(-d^2/32), d = i-16, computed offline (theta = 4).
__device__ constexpr float WG[NT] = {
  0.000335463f, 0.000883827f, 0.002187492f, 0.005086072f, 0.011108997f,
  0.022794173f, 0.043936928f, 0.079559512f, 0.135335283f, 0.216265076f,
  0.324652467f, 0.457833362f, 0.606530660f, 0.754839602f, 0.882496903f,
  0.969233234f, 1.0f,         0.969233234f, 0.882496903f, 0.754839602f,
  0.606530660f, 0.457833362f, 0.324652467f, 0.216265076f, 0.135335283f,
  0.079559512f, 0.043936928f, 0.022794173f, 0.011108997f, 0.005086072f,
  0.002187492f, 0.000883827f, 0.000335463f
};

__device__ constexpr float wg_sum() {
  float s = 0.0f;
  for (int i = 0; i < NT; ++i) s += WG[i];
  return s;
}

// weight with range clamp, compile-time foldable
__device__ __forceinline__ constexpr float Wc(int j) {
  return (j >= 0 && j < NT) ? WG[j] : 0.0f;
}

__device__ __forceinline__ u16 f2bf(float f) {  // round-to-nearest-even
  u32 u = __float_as_uint(f);
  u += 0x7fffu + ((u >> 16) & 1u);
  return (u16)(u >> 16);
}
__device__ __forceinline__ float bf2f(u16 v) { return __uint_as_float(((u32)v) << 16); }
__device__ __forceinline__ float bflo(u32 v) { return __uint_as_float(v << 16); }
__device__ __forceinline__ float bfhi(u32 v) { return __uint_as_float(v & 0xffff0000u); }

// edge-aware 1D window weight at coordinate u in [0, n)
__device__ __forceinline__ float win_w(int u, int n) {
  constexpr float S = wg_sum();
  if (u >= RR && u < n - RR) return S;
  float w = 0.0f;
#pragma unroll
  for (int i = 0; i < NT; ++i) {
    const int uu = u - RR + i;
    if (uu >= 0 && uu < n) w += WG[i];
  }
  return w;
}

// ---------------------------------------------------------------------------
// K0: pointwise products -> 25 bf16 planes. 2 px/thread, u32 packed stores.
// Grid (HW/512, B), block 256.
// [0..2]=I, [3..6]=p, [7..18]=I_c*p_k (c*4+k), [19..24]=I_cI_c' sym.
// ---------------------------------------------------------------------------
__global__ __launch_bounds__(256) void k_products(const float* __restrict__ I,
                                                  const float* __restrict__ P,
                                                  u16* __restrict__ WS) {
  const int batch = blockIdx.y;
  const int t = blockIdx.x * 256 + threadIdx.x;  // pair index
  const float2* i2 = reinterpret_cast<const float2*>(I + (size_t)batch * HWSZ * 3);
  const float2 a = i2[3 * t], b = i2[3 * t + 1], c = i2[3 * t + 2];
  // px0: a.x a.y b.x   px1: b.y c.x c.y
  const float4* p4 = reinterpret_cast<const float4*>(P + (size_t)batch * HWSZ * 4);
  const float4 q0 = p4[2 * t], q1 = p4[2 * t + 1];

  const float iA[3] = {a.x, a.y, b.x};
  const float iB[3] = {b.y, c.x, c.y};
  const float pA[4] = {q0.x, q0.y, q0.z, q0.w};
  const float pB[4] = {q1.x, q1.y, q1.z, q1.w};

  u32* dst = reinterpret_cast<u32*>(WS + (size_t)batch * REG_U16 + PR_OFF) + t;
  const int half = HWSZ / 2;
#define ST(ch, va, vb) dst[(ch) * half] = (u32)f2bf(va) | ((u32)f2bf(vb) << 16)
  ST(0, iA[0], iB[0]); ST(1, iA[1], iB[1]); ST(2, iA[2], iB[2]);
  ST(3, pA[0], pB[0]); ST(4, pA[1], pB[1]); ST(5, pA[2], pB[2]); ST(6, pA[3], pB[3]);
#pragma unroll
  for (int cc = 0; cc < 3; ++cc)
#pragma unroll
    for (int k = 0; k < 4; ++k)
      ST(7 + cc * 4 + k, iA[cc] * pA[k], iB[cc] * pB[k]);
  ST(19, iA[0] * iA[0], iB[0] * iB[0]);
  ST(20, iA[0] * iA[1], iB[0] * iB[1]);
  ST(21, iA[0] * iA[2], iB[0] * iB[2]);
  ST(22, iA[1] * iA[1], iB[1] * iB[1]);
  ST(23, iA[1] * iA[2], iB[1] * iB[2]);
  ST(24, iA[2] * iA[2], iB[2] * iB[2]);
#undef ST
}

// ---------------------------------------------------------------------------
// K1: horizontal blur of NPL bf16 planes -> bf16. One full row per block,
//     4 outputs/thread; FMA over tap pairs via packed fp32 (R18).
//     Grid (H, NPL, B), block 256. srcOff/dstOff are u16 offsets in region.
// ---------------------------------------------------------------------------
__global__ __launch_bounds__(256) void k_hblur_bf(const u16* __restrict__ WS_c,
                                                  u16* __restrict__ WS,
                                                  size_t srcOff, size_t dstOff) {
  __shared__ float s[1056];  // 16 halo | 1024 row | 16 halo
  const int tid = threadIdx.x;
  const int y = blockIdx.x;
  const int ch = blockIdx.y;
  const int batch = blockIdx.z;
  const u16* src = WS_c + (size_t)batch * REG_U16 + srcOff +
                   (size_t)ch * HWSZ + y * WW;
  if (tid < 16) { s[tid] = 0.0f; s[1040 + tid] = 0.0f; }
  {
    const uint2 v = *reinterpret_cast<const uint2*>(src + 4 * tid);
    float4 f;
    f.x = bf2f((u16)v.x);
    f.y = bf2f((u16)(v.x >> 16));
    f.z = bf2f((u16)v.y);
    f.w = bf2f((u16)(v.y >> 16));
    *reinterpret_cast<float4*>(&s[16 + 4 * tid]) = f;
  }
  __syncthreads();

  // outputs x=4t+k (k=0..3); window of out k covers s[4t+k .. 4t+k+32],
  // i.e. vals index j = 4*r4 + e with weight Wc(j - k).
  v2f acc[4];
#pragma unroll
  for (int k = 0; k < 4; ++k) acc[k] = (v2f){0.0f, 0.0f};
  {
    const float4* s4 = reinterpret_cast<const float4*>(s) + tid;
#pragma unroll
    for (int r4 = 0; r4 < 9; ++r4) {
      const float4 q = s4[r4];
      const v2f v01 = {q.x, q.y};
      const v2f v23 = {q.z, q.w};
#pragma unroll
      for (int k = 0; k < 4; ++k) {
        const int j0 = 4 * r4 - k;
        if (Wc(j0) != 0.0f || Wc(j0 + 1) != 0.0f)
          acc[k] += (v2f){Wc(j0), Wc(j0 + 1)} * v01;
        if (Wc(j0 + 2) != 0.0f || Wc(j0 + 3) != 0.0f)
          acc[k] += (v2f){Wc(j0 + 2), Wc(j0 + 3)} * v23;
      }
    }
  }
  float out[4];
#pragma unroll
  for (int k = 0; k < 4; ++k) out[k] = acc[k].x + acc[k].y;

  const u32 lo = (u32)f2bf(out[0]) | ((u32)f2bf(out[1]) << 16);
  const u32 hi = (u32)f2bf(out[2]) | ((u32)f2bf(out[3]) << 16);
  u16* dst = WS + (size_t)batch * REG_U16 + dstOff + (size_t)ch * HWSZ + y * WW;
  *reinterpret_cast<uint2*>(dst + 4 * tid) = make_uint2(lo, hi);
}

// ---------------------------------------------------------------------------
// K2: pure vertical blur of bf16 planes, LDS-staged 96x128 tile (24 KiB).
//     R19 mapping: thread = column-pair cp (tid&63) x 16 rows (grp=tid>>6).
//     u32 LDS reads (2 cols), pk-FMA across columns, packed u32 stores.
//     Grid (W/128, H/64, NPL*B), block 256.
// ---------------------------------------------------------------------------
__global__ __launch_bounds__(256) void k_vblur(const u16* __restrict__ WS_c,
                                               u16* __restrict__ WS,
                                               size_t srcOff, size_t dstOff,
                                               int npl) {
  __shared__ u16 s[VROWS][VCOLS];  // 96 x 128 u16 = 24 KiB
  const int tid = threadIdx.x;
  const int bz = blockIdx.z;
  const int batch = bz / npl;
  const int ch = bz - batch * npl;
  const int xb = blockIdx.x * VCOLS;
  const int y0 = blockIdx.y * VBY;
  const int cp = tid & 63;    // column pair: cols 2cp, 2cp+1
  const int grp = tid >> 6;   // 0..3, 16 output rows each

  {
    const u16* src = WS_c + (size_t)batch * REG_U16 + srcOff +
                     (size_t)ch * HWSZ + xb;
    uint4 tmp[6];
#pragma unroll
    for (int it = 0; it < 6; ++it) {
      const int id = it * 256 + tid;
      const int row = id >> 4;          // 0..95
      const int cir = id & 15;          // 16B chunk within row
      const int gy = y0 - RR + row;
      uint4 v = make_uint4(0u, 0u, 0u, 0u);
      if (gy >= 0 && gy < HH)
        v = *reinterpret_cast<const uint4*>(src + (size_t)gy * WW + cir * 8);
      tmp[it] = v;
    }
#pragma unroll
    for (int it = 0; it < 6; ++it) {
      const int id = it * 256 + tid;
      const int row = id >> 4;
      const int cir = id & 15;
      *reinterpret_cast<uint4*>(&s[row][cir * 8]) = tmp[it];
    }
  }
  __syncthreads();

  const u32* scol = reinterpret_cast<const u32*>(&s[0][0]) + cp;  // stride 64/row
  u16* dst = WS + (size_t)batch * REG_U16 + dstOff +
             (size_t)ch * HWSZ + xb + 2 * cp;

  for (int c = 0; c < 2; ++c) {  // 2 chunks of 8 output rows
    const int cb = grp * 16 + c * 8;  // staged-row base of this chunk
    v2f a[8];
#pragma unroll
    for (int t = 0; t < 8; ++t) a[t] = (v2f){0.0f, 0.0f};
#pragma unroll
    for (int r = 0; r < 40; ++r) {
      const u32 v = scol[(cb + r) * 64];
      const v2f vv = {bflo(v), bfhi(v)};
#pragma unroll
      for (int t = 0; t < 8; ++t) {
        const int dy = r - t;
        if (dy >= 0 && dy < NT) {
          const v2f w = {WG[dy], WG[dy]};
          a[t] += w * vv;
        }
      }
    }
#pragma unroll
    for (int t = 0; t < 8; ++t) {
      const int yy = y0 + cb + t;
      const u32 pair = (u32)f2bf(a[t].x) | ((u32)f2bf(a[t].y) << 16);
      *reinterpret_cast<u32*>(dst + (size_t)yy * WW) = pair;
    }
  }
}

// ---------------------------------------------------------------------------
// K3: normalize (center subtract + /N) + pointwise 3x3 SPD solve with 4 RHS
//     -> 16 bf16 planes (a: c*4+k, b: 12+k) + fp32 s0[pix*4+k] = sum a*I_c+b.
//     Grid (HW/256, B), block 256.
// ---------------------------------------------------------------------------
__global__ __launch_bounds__(256) void k_solve(u16* __restrict__ WS,
                                               const float* __restrict__ I_,
                                               const float* __restrict__ P_) {
  const int batch = blockIdx.y;
  const int i = blockIdx.x * 256 + threadIdx.x;
  const int y = i >> 10;
  const int x = i & 1023;
  u16* reg = WS + (size_t)batch * REG_U16;
  const u16* M = reg + M_OFF;
  u16* AB = reg + AB_OFF;
  float* S0 = reinterpret_cast<float*>(reg + S0_OFF);
  const float* I = I_ + (size_t)batch * HWSZ * 3;
  const float* P = P_ + (size_t)batch * HWSZ * 4;
  const float invN = __builtin_amdgcn_rcpf(win_w(x, WW) * win_w(y, HH) - 1.0f);

  const float I0 = I[i * 3], I1 = I[i * 3 + 1], I2 = I[i * 3 + 2];
  float p[4];
#pragma unroll
  for (int k = 0; k < 4; ++k) p[k] = P[i * 4 + k];

  const float mI0 = (bf2f(M[i]) - I0) * invN;
  const float mI1 = (bf2f(M[HWSZ + i]) - I1) * invN;
  const float mI2 = (bf2f(M[2 * HWSZ + i]) - I2) * invN;
  float mp[4];
#pragma unroll
  for (int k = 0; k < 4; ++k) mp[k] = (bf2f(M[(3 + k) * HWSZ + i]) - p[k]) * invN;
  float cov[12];
#pragma unroll
  for (int k = 0; k < 4; ++k) {
    cov[k]     = (bf2f(M[(7 + k) * HWSZ + i])  - I0 * p[k]) * invN - mI0 * mp[k];
    cov[4 + k] = (bf2f(M[(11 + k) * HWSZ + i]) - I1 * p[k]) * invN - mI1 * mp[k];
    cov[8 + k] = (bf2f(M[(15 + k) * HWSZ + i]) - I2 * p[k]) * invN - mI2 * mp[k];
  }
  const float A00 = (bf2f(M[19 * HWSZ + i]) - I0 * I0) * invN - mI0 * mI0 + EPSF;
  const float A01 = (bf2f(M[20 * HWSZ + i]) - I0 * I1) * invN - mI0 * mI1;
  const float A02 = (bf2f(M[21 * HWSZ + i]) - I0 * I2) * invN - mI0 * mI2;
  const float A11 = (bf2f(M[22 * HWSZ + i]) - I1 * I1) * invN - mI1 * mI1 + EPSF;
  const float A12 = (bf2f(M[23 * HWSZ + i]) - I1 * I2) * invN - mI1 * mI2;
  const float A22 = (bf2f(M[24 * HWSZ + i]) - I2 * I2) * invN - mI2 * mI2 + EPSF;
  const float c00 = A11 * A22 - A12 * A12;
  const float c01 = A02 * A12 - A01 * A22;
  const float c02 = A01 * A12 - A02 * A11;
  const float det = A00 * c00 + A01 * c01 + A02 * c02;
  const float idet = 1.0f / det;
  const float i00 = c00 * idet, i01 = c01 * idet, i02 = c02 * idet;
  const float i11 = (A00 * A22 - A02 * A02) * idet;
  const float i12 = (A01 * A02 - A00 * A12) * idet;
  const float i22 = (A00 * A11 - A01 * A01) * idet;
  float4 s0;
  float* s0p = &s0.x;
#pragma unroll
  for (int k = 0; k < 4; ++k) {
    const float a0 = i00 * cov[k] + i01 * cov[4 + k] + i02 * cov[8 + k];
    const float a1 = i01 * cov[k] + i11 * cov[4 + k] + i12 * cov[8 + k];
    const float a2 = i02 * cov[k] + i12 * cov[4 + k] + i22 * cov[8 + k];
    const float b = mp[k] - (a0 * mI0 + a1 * mI1 + a2 * mI2);
    AB[k * HWSZ + i] = f2bf(a0);
    AB[(4 + k) * HWSZ + i] = f2bf(a1);
    AB[(8 + k) * HWSZ + i] = f2bf(a2);
    AB[(12 + k) * HWSZ + i] = f2bf(b);
    s0p[k] = a0 * I0 + a1 * I1 + a2 * I2 + b;
  }
  *reinterpret_cast<float4*>(S0 + (size_t)i * 4) = s0;
}

// ---------------------------------------------------------------------------
// K5b: combine q_k = (sum_c m~_a[c,k]*I_c + m~_b[k] - s0_k) * invN.
//      m~ are RAW blurs (bf16).  Grid (HW/256, B), block 256.
// ---------------------------------------------------------------------------
__global__ __launch_bounds__(256) void k_combine(const u16* __restrict__ WS,
                                                 const float* __restrict__ I_,
                                                 float* __restrict__ out_) {
  const int batch = blockIdx.y;
  const int i = blockIdx.x * 256 + threadIdx.x;
  const int y = i >> 10;
  const int x = i & 1023;
  const u16* reg = WS + (size_t)batch * REG_U16;
  const u16* MB = reg + MB_OFF;
  const float* S0 = reinterpret_cast<const float*>(reg + S0_OFF);
  const float* I = I_ + (size_t)batch * HWSZ * 3;
  float* out = out_ + (size_t)batch * HWSZ * 4;
  const float invN = __builtin_amdgcn_rcpf(win_w(x, WW) * win_w(y, HH) - 1.0f);
  float m[16];
#pragma unroll
  for (int ch = 0; ch < 16; ++ch) m[ch] = bf2f(MB[(size_t)ch * HWSZ + i]);
  const float i0 = I[i * 3], i1 = I[i * 3 + 1], i2 = I[i * 3 + 2];
  const float4 s0 = *reinterpret_cast<const float4*>(S0 + (size_t)i * 4);
  float4 q;
  q.x = (m[0] * i0 + m[4] * i1 + m[8]  * i2 + m[12] - s0.x) * invN;
  q.y = (m[1] * i0 + m[5] * i1 + m[9]  * i2 + m[13] - s0.y) * invN;
  q.z = (m[2] * i0 + m[6] * i1 + m[10] * i2 + m[14] - s0.z) * invN;
  q.w = (m[3] * i0 + m[7] * i1 + m[11] * i2 + m[15] - s0.w) * invN;
  *reinterpret_cast<float4*>(out + (size_t)i * 4) = q;
}

extern "C" void kernel_launch(void* const* d_in, const int* in_sizes, int n_in,
                              void* d_out, int out_size, void* d_ws, size_t ws_size,
                              hipStream_t stream) {
  const float* I = (const float*)d_in[0];
  const float* P = (const float*)d_in[1];
  float* out = (float*)d_out;
  u16* WS = (u16*)d_ws;  // 2 regions x 50 bf16 planes = 200 MB

  k_products<<<dim3(HWSZ / 512, 2), dim3(256), 0, stream>>>(I, P, WS);
  k_hblur_bf<<<dim3(HH, 25, 2), dim3(256), 0, stream>>>(WS, WS, PR_OFF, HB1_OFF);
  k_vblur<<<dim3(WW / VCOLS, HH / VBY, 25 * 2), dim3(256), 0, stream>>>(
      WS, WS, HB1_OFF, M_OFF, 25);
  k_solve<<<dim3(HWSZ / 256, 2), dim3(256), 0, stream>>>(WS, I, P);
  k_hblur_bf<<<dim3(HH, 16, 2), dim3(256), 0, stream>>>(WS, WS, AB_OFF, HB2_OFF);
  k_vblur<<<dim3(WW / VCOLS, HH / VBY, 16 * 2), dim3(256), 0, stream>>>(
      WS, WS, HB2_OFF, MB_OFF, 16);
  k_combine<<<dim3(HWSZ / 256, 2), dim3(256), 0, stream>>>(WS, I, out);
}